// Round 5
// baseline (105.293 us; speedup 1.0000x reference)
//
#include <hip/hip_runtime.h>
#include <cstdint>

#define NEMB   512     // codebook entries
#define DQ     64      // quantized vector dim (in_mem*out_mem)
#define NROWS  4096    // in_g*out_g weight rows
#define BATCH  8192
#define KDIM   512     // in_g*in_mem
#define NDIM   512     // out_g*out_mem

#define VQ_BLOCKS 512  // 8 weight rows each

typedef __attribute__((ext_vector_type(8))) short bf16x8;
typedef __attribute__((ext_vector_type(4))) float floatx4;

__device__ __forceinline__ unsigned short f2bf(float f) {
    unsigned int u = __float_as_uint(f);
    u += 0x7fffu + ((u >> 16) & 1u);     // RNE
    return (unsigned short)(u >> 16);
}

__device__ __forceinline__ void async16(const void* g, void* l) {
    __builtin_amdgcn_global_load_lds(
        (const __attribute__((address_space(1))) void*)g,
        (__attribute__((address_space(3))) void*)l, 16, 0, 0);
}

// ---------------------------------------------------------------------------
// Kernel 1: VQ argmin (f64) -> W^T bf16 + diff partials. 512 blocks x 8 rows.
// Per-thread state sized to fit registers: acc[2][8] f64 = 32 VGPRs (the R2/R3
// spill lesson). e2 norms once per block into LDS.
// ---------------------------------------------------------------------------
__global__ __launch_bounds__(256) void vq_kernel(
    const float* __restrict__ weight,   // [4096][64]
    const float* __restrict__ embed,    // [64][512]
    unsigned short* __restrict__ wt,    // bf16 W^T [512][512]  (wt[n][k])
    float* __restrict__ partials,       // [512] diff partial sums
    const int* __restrict__ use_qw)
{
    const int t    = threadIdx.x;
    const int bid  = blockIdx.x;
    const int wave = t >> 6;
    const int lane = t & 63;
    const int rblk = bid * 8;
    const bool qon = (use_qw[0] != 0);

    __shared__ float  wlds[8 * 64];      // 2 KB: block's 8 weight rows
    __shared__ double e2lds[NEMB];       // 4 KB: candidate squared norms
    __shared__ int    bidx_lds[8];

    if (t < 128)
        reinterpret_cast<float4*>(wlds)[t] =
            reinterpret_cast<const float4*>(weight + (size_t)rblk * 64)[t];

    {   // e2 pre-phase: thread t -> candidates 2t, 2t+1 (float2 coalesced)
        double s0 = 0.0, s1 = 0.0;
        for (int d = 0; d < DQ; ++d) {
            const float2 e = *reinterpret_cast<const float2*>(embed + d * NEMB + 2 * t);
            s0 = fma((double)e.x, (double)e.x, s0);
            s1 = fma((double)e.y, (double)e.y, s1);
        }
        e2lds[2 * t]     = s0;
        e2lds[2 * t + 1] = s1;
    }
    __syncthreads();

    if (qon) {
        const int j0 = lane * 8;         // this lane's 8 contiguous candidates
        const int r0 = wave * 2;         // wave's first local row

        double a0[8], a1[8];
#pragma unroll
        for (int c = 0; c < 8; ++c) { a0[c] = 0.0; a1[c] = 0.0; }

        for (int d = 0; d < DQ; ++d) {
            const float4 ea = *reinterpret_cast<const float4*>(embed + d * NEMB + j0);
            const float4 eb = *reinterpret_cast<const float4*>(embed + d * NEMB + j0 + 4);
            double ev[8];
            ev[0] = (double)ea.x; ev[1] = (double)ea.y; ev[2] = (double)ea.z; ev[3] = (double)ea.w;
            ev[4] = (double)eb.x; ev[5] = (double)eb.y; ev[6] = (double)eb.z; ev[7] = (double)eb.w;
            const double w0 = (double)wlds[r0 * 64 + d];        // LDS broadcast
            const double w1 = (double)wlds[r0 * 64 + 64 + d];
#pragma unroll
            for (int c = 0; c < 8; ++c) a0[c] = fma(w0, ev[c], a0[c]);
#pragma unroll
            for (int c = 0; c < 8; ++c) a1[c] = fma(w1, ev[c], a1[c]);
        }

#pragma unroll
        for (int r = 0; r < 2; ++r) {
            double best = 1e300;
            int bi = 0;
#pragma unroll
            for (int c = 0; c < 8; ++c) {
                const double q = fma(-2.0, (r == 0 ? a0[c] : a1[c]), e2lds[j0 + c]);
                if (q < best) { best = q; bi = j0 + c; }   // ascending j keeps lowest idx
            }
#pragma unroll
            for (int off = 1; off < 64; off <<= 1) {
                const double ob = __shfl_xor(best, off, 64);
                const int    oi = __shfl_xor(bi,   off, 64);
                if (ob < best || (ob == best && oi < bi)) { best = ob; bi = oi; }
            }
            if (lane == 0) bidx_lds[r0 + r] = bi;
        }
    }
    __syncthreads();

    // ---- write phase: 64 threads; thread = (row, om); 16 B coalesced store ----
    float dsum = 0.f;
    if (t < 64) {
        const int rloc = t >> 3, om = t & 7;
        const int row = rblk + rloc;
        const int g = row >> 6, og = row & 63;
        const int bidx = qon ? bidx_lds[rloc] : 0;
        alignas(16) unsigned short q8[8];
#pragma unroll
        for (int i = 0; i < 8; ++i) {
            const int d = i * 8 + om;
            const float wv = wlds[rloc * 64 + d];
            float qv;
            if (qon) {
                qv = embed[d * NEMB + bidx];
                const float df = qv - wv;
                dsum = fmaf(df, df, dsum);
            } else {
                qv = wv;
            }
            q8[i] = f2bf(qv);
        }
        // W[k = g*8+i][n = og*8+om] -> wt[n*KDIM + k]; 8 consecutive k = 16 B
        *reinterpret_cast<int4*>(wt + (size_t)(og * 8 + om) * KDIM + g * 8) =
            *reinterpret_cast<const int4*>(q8);
    }
    if (wave == 0) {                     // only wave 0 holds nonzero dsum
#pragma unroll
        for (int off = 32; off > 0; off >>= 1) dsum += __shfl_down(dsum, off, 64);
        if (lane == 0) partials[bid] = dsum;
    }
}

// ---------------------------------------------------------------------------
// Kernel 2: res = x[8192,512](fp32) @ wt^T (bf16). A staged fp32 straight from
// x via global_load_lds (no xb round-trip); converted to bf16 (RNE) at
// fragment-read time -- the K-loop is barrier-bound, the cvt VALU is free.
// 128x64 tile, BK=64, 4 waves (2m x 2n, each 64x32).
// A swizzle: 16-B chunk c of row r stored at position c^(r&15) (256 B fp32 row
// stride -> unswizzled b128 reads would be 16-way bank conflicts; swizzled
// reads are 2-way = free). B swizzle: c^(r&7) over 8 chunks (as R4).
// Grid 512 = 2 blocks/CU; XCD swizzle keeps one 128-row fp32 stripe per XCD L2.
// ---------------------------------------------------------------------------
__global__ __launch_bounds__(256) void gemm_kernel(
    const float* __restrict__ x,             // fp32 [8192][512]
    const unsigned short* __restrict__ wt,   // bf16 [512][512]
    float* __restrict__ out,                 // fp32 [8192][512]
    const float* __restrict__ partials,      // [512]
    float* diff_slot)
{
    __shared__ float          Asf[128 * 64]; // 32 KB [m][k] fp32, xor-swizzled
    __shared__ unsigned short Bs[64 * 64];   //  8 KB [n][k] bf16, xor-swizzled

    const int tid  = threadIdx.x;
    const int wave = tid >> 6;
    const int lane = tid & 63;

    // block swizzle: XCD x (= flat&7 heuristic) owns m-tiles [x*8, x*8+8)
    const int flat = blockIdx.x;             // 0..511
    const int xcd  = flat & 7;
    const int sub  = flat >> 3;              // 0..63
    const int nt   = sub & 7;
    const int mt   = xcd * 8 + (sub >> 3);   // 0..63
    const int m0 = mt * 128;
    const int n0 = nt * 64;
    const int wm = (wave >> 1) * 64;
    const int wn = (wave & 1) * 32;

    // A staging: groups of 4 rows; lane -> (row, dest chunk pos), source chunk
    // is the one whose swizzled position equals (lane&15).
    const int srowA = lane >> 4;             // row within 4-row group
    const int posA  = lane & 15;             // dest chunk position
    // B staging: groups of 8 rows (8 chunks/row)
    const int srowB   = lane >> 3;
    const int schunkB = (lane & 7) ^ srowB;
    // fragments
    const int mrow = lane & 15;
    const int cq   = lane >> 4;              // 0..3

    floatx4 acc[4][2] = {};

    for (int k0 = 0; k0 < KDIM; k0 += 64) {
        __syncthreads();
#pragma unroll
        for (int c = 0; c < 8; ++c) {        // A: 32 groups of 4 rows; 8/wave
            const int g = wave * 8 + c;
            const int rloc = g * 4 + srowA;                 // 0..127
            const int cA = posA ^ (rloc & 15);              // logical source chunk
            async16(x + (size_t)(m0 + rloc) * KDIM + k0 + cA * 4,
                    (char*)Asf + g * 1024);
        }
#pragma unroll
        for (int c = 0; c < 2; ++c) {        // B: 8 groups of 8 rows; 2/wave
            const int g = wave * 2 + c;
            const int rloc = g * 8 + srowB;
            async16(wt + (size_t)(n0 + rloc) * KDIM + k0 + schunkB * 8,
                    (char*)Bs + g * 1024);
        }
        __syncthreads();

#pragma unroll
        for (int ks = 0; ks < 2; ++ks) {
            bf16x8 a[4], b[2];
#pragma unroll
            for (int i = 0; i < 4; ++i) {
                const int r = wm + i * 16 + mrow;
                const int c0 = ks * 8 + cq * 2;             // fp32 16-B chunk ids
                const floatx4 f0 = *reinterpret_cast<const floatx4*>(
                    &Asf[r * 64 + ((c0 ^ (r & 15)) * 4)]);
                const floatx4 f1 = *reinterpret_cast<const floatx4*>(
                    &Asf[r * 64 + (((c0 + 1) ^ (r & 15)) * 4)]);
                bf16x8 v;
                v[0] = (short)f2bf(f0.x); v[1] = (short)f2bf(f0.y);
                v[2] = (short)f2bf(f0.z); v[3] = (short)f2bf(f0.w);
                v[4] = (short)f2bf(f1.x); v[5] = (short)f2bf(f1.y);
                v[6] = (short)f2bf(f1.z); v[7] = (short)f2bf(f1.w);
                a[i] = v;
            }
#pragma unroll
            for (int j = 0; j < 2; ++j) {
                const int r = wn + j * 16 + mrow;
                const int c = ks * 4 + cq;
                b[j] = *reinterpret_cast<const bf16x8*>(&Bs[r * 64 + ((c ^ (r & 7)) * 8)]);
            }
#pragma unroll
            for (int i = 0; i < 4; ++i)
#pragma unroll
                for (int j = 0; j < 2; ++j)
                    acc[i][j] = __builtin_amdgcn_mfma_f32_16x16x32_bf16(a[i], b[j], acc[i][j], 0, 0, 0);
        }
    }

    // C/D layout: col = lane&15, row = (lane>>4)*4 + reg  (m89-verified)
    const int col = lane & 15;
    const int rbase = (lane >> 4) * 4;
#pragma unroll
    for (int i = 0; i < 4; ++i)
#pragma unroll
        for (int j = 0; j < 2; ++j)
#pragma unroll
            for (int r = 0; r < 4; ++r) {
                const int mm = m0 + wm + i * 16 + rbase + r;
                const int nn = n0 + wn + j * 16 + col;
                out[(size_t)mm * NDIM + nn] = acc[i][j][r];
            }

    // diff reduction (one wave of one block)
    if (flat == 0 && wave == 0 && diff_slot) {
        float s = 0.f;
#pragma unroll
        for (int q = 0; q < 8; ++q) s += partials[lane + 64 * q];
#pragma unroll
        for (int off = 32; off > 0; off >>= 1) s += __shfl_down(s, off, 64);
        if (lane == 0) diff_slot[0] = s * (1.f / (NROWS * DQ));
    }
}

// ---------------------------------------------------------------------------
extern "C" void kernel_launch(void* const* d_in, const int* in_sizes, int n_in,
                              void* d_out, int out_size, void* d_ws, size_t ws_size,
                              hipStream_t stream)
{
    const float* x      = (const float*)d_in[0];
    const float* weight = (const float*)d_in[1];
    const float* embed  = (const float*)d_in[2];
    const int*   use_qw = (const int*)d_in[3];
    float* out = (float*)d_out;

    // ws layout: [0,512K) W^T bf16 ; [512K,514K) diff partials
    unsigned short* wt = (unsigned short*)d_ws;
    float* partials    = (float*)((char*)d_ws + (512u << 10));

    float* diff_slot = (out_size > BATCH * NDIM) ? (out + (size_t)BATCH * NDIM) : nullptr;

    vq_kernel<<<VQ_BLOCKS, 256, 0, stream>>>(weight, embed, wt, partials, use_qw);
    gemm_kernel<<<512, 256, 0, stream>>>(x, wt, out, partials, diff_slot);
}

// Round 6
// 99.099 us; speedup vs baseline: 1.0625x; 1.0625x over previous
//
#include <hip/hip_runtime.h>
#include <cstdint>

#define NEMB   512     // codebook entries
#define DQ     64      // quantized vector dim (in_mem*out_mem)
#define NROWS  4096    // in_g*out_g weight rows
#define BATCH  8192
#define KDIM   512     // in_g*in_mem
#define NDIM   512     // out_g*out_mem

#define VQ_BLOCKS   512    // 8 weight rows each; FIRST in grid (co-schedule w/ conv)
#define CONV_BLOCKS 2048

typedef __attribute__((ext_vector_type(8))) short bf16x8;
typedef __attribute__((ext_vector_type(4))) float floatx4;

__device__ __forceinline__ unsigned short f2bf(float f) {
    unsigned int u = __float_as_uint(f);
    u += 0x7fffu + ((u >> 16) & 1u);     // RNE
    return (unsigned short)(u >> 16);
}

__device__ __forceinline__ void async16(const void* g, void* l) {
    __builtin_amdgcn_global_load_lds(
        (const __attribute__((address_space(1))) void*)g,
        (__attribute__((address_space(3))) void*)l, 16, 0, 0);
}

// ---------------------------------------------------------------------------
// Kernel 1 (fused, R4-verbatim): blocks [0,512) = VQ (8 rows each);
// blocks [512,2560) = x fp32->bf16 conversion. VQ per-thread state sized to
// FIT REGISTERS: acc[2][8] f64 = 32 VGPRs (R2/R3 spilled acc[4][8]).
// ---------------------------------------------------------------------------
__global__ __launch_bounds__(256) void fused_prep_vq(
    const float* __restrict__ x,        // [8192*512]
    const float* __restrict__ weight,   // [4096][64]
    const float* __restrict__ embed,    // [64][512]
    unsigned short* __restrict__ xb,    // bf16 out [8192*512]
    unsigned short* __restrict__ wt,    // bf16 W^T [512][512]  (wt[n][k])
    float* __restrict__ partials,       // [512] diff partial sums
    const int* __restrict__ use_qw)
{
    const int t   = threadIdx.x;
    const int bid = blockIdx.x;

    if (bid >= VQ_BLOCKS) {             // ---- x conversion ----
        const int gid = (bid - VQ_BLOCKS) * 256 + t;
#pragma unroll
        for (int it = 0; it < 2; ++it) {
            const int idx = gid + it * 524288;        // float4 index < 1048576
            float4 v = reinterpret_cast<const float4*>(x)[idx];
            ushort4 o;
            o.x = f2bf(v.x); o.y = f2bf(v.y); o.z = f2bf(v.z); o.w = f2bf(v.w);
            reinterpret_cast<ushort4*>(xb)[idx] = o;
        }
        return;
    }

    // ---- VQ part: 8 rows, 4 waves, 2 rows/wave, 8 candidates/lane ----
    const int wave = t >> 6;
    const int lane = t & 63;
    const int rblk = bid * 8;
    const bool qon = (use_qw[0] != 0);

    __shared__ float  wlds[8 * 64];      // 2 KB: block's 8 weight rows
    __shared__ double e2lds[NEMB];       // 4 KB: candidate squared norms
    __shared__ int    bidx_lds[8];

    if (t < 128)
        reinterpret_cast<float4*>(wlds)[t] =
            reinterpret_cast<const float4*>(weight + (size_t)rblk * 64)[t];

    {   // e2 pre-phase: thread t -> candidates 2t, 2t+1 (float2 coalesced)
        double s0 = 0.0, s1 = 0.0;
        for (int d = 0; d < DQ; ++d) {
            const float2 e = *reinterpret_cast<const float2*>(embed + d * NEMB + 2 * t);
            s0 = fma((double)e.x, (double)e.x, s0);
            s1 = fma((double)e.y, (double)e.y, s1);
        }
        e2lds[2 * t]     = s0;
        e2lds[2 * t + 1] = s1;
    }
    __syncthreads();

    if (qon) {
        const int j0 = lane * 8;         // this lane's 8 contiguous candidates
        const int r0 = wave * 2;         // wave's first local row

        double a0[8], a1[8];
#pragma unroll
        for (int c = 0; c < 8; ++c) { a0[c] = 0.0; a1[c] = 0.0; }

        for (int d = 0; d < DQ; ++d) {
            const float4 ea = *reinterpret_cast<const float4*>(embed + d * NEMB + j0);
            const float4 eb = *reinterpret_cast<const float4*>(embed + d * NEMB + j0 + 4);
            double ev[8];
            ev[0] = (double)ea.x; ev[1] = (double)ea.y; ev[2] = (double)ea.z; ev[3] = (double)ea.w;
            ev[4] = (double)eb.x; ev[5] = (double)eb.y; ev[6] = (double)eb.z; ev[7] = (double)eb.w;
            const double w0 = (double)wlds[r0 * 64 + d];        // LDS broadcast
            const double w1 = (double)wlds[r0 * 64 + 64 + d];
#pragma unroll
            for (int c = 0; c < 8; ++c) a0[c] = fma(w0, ev[c], a0[c]);
#pragma unroll
            for (int c = 0; c < 8; ++c) a1[c] = fma(w1, ev[c], a1[c]);
        }

#pragma unroll
        for (int r = 0; r < 2; ++r) {
            double best = 1e300;
            int bi = 0;
#pragma unroll
            for (int c = 0; c < 8; ++c) {
                const double q = fma(-2.0, (r == 0 ? a0[c] : a1[c]), e2lds[j0 + c]);
                if (q < best) { best = q; bi = j0 + c; }   // ascending j keeps lowest idx
            }
#pragma unroll
            for (int off = 1; off < 64; off <<= 1) {
                const double ob = __shfl_xor(best, off, 64);
                const int    oi = __shfl_xor(bi,   off, 64);
                if (ob < best || (ob == best && oi < bi)) { best = ob; bi = oi; }
            }
            if (lane == 0) bidx_lds[r0 + r] = bi;
        }
    }
    __syncthreads();

    // ---- write phase: 64 threads; thread = (row, om); 16 B coalesced store ----
    float dsum = 0.f;
    if (t < 64) {
        const int rloc = t >> 3, om = t & 7;
        const int row = rblk + rloc;
        const int g = row >> 6, og = row & 63;
        const int bidx = qon ? bidx_lds[rloc] : 0;
        alignas(16) unsigned short q8[8];
#pragma unroll
        for (int i = 0; i < 8; ++i) {
            const int d = i * 8 + om;
            const float wv = wlds[rloc * 64 + d];
            float qv;
            if (qon) {
                qv = embed[d * NEMB + bidx];
                const float df = qv - wv;
                dsum = fmaf(df, df, dsum);
            } else {
                qv = wv;
            }
            q8[i] = f2bf(qv);
        }
        // W[k = g*8+i][n = og*8+om] -> wt[n*KDIM + k]; 8 consecutive k = 16 B
        *reinterpret_cast<int4*>(wt + (size_t)(og * 8 + om) * KDIM + g * 8) =
            *reinterpret_cast<const int4*>(q8);
    }
    if (wave == 0) {                     // only wave 0 holds nonzero dsum
#pragma unroll
        for (int off = 32; off > 0; off >>= 1) dsum += __shfl_down(dsum, off, 64);
        if (lane == 0) partials[bid] = dsum;
    }
}

// ---------------------------------------------------------------------------
// Kernel 2: res = xb[8192,512] @ wt^T   (wt stored [N][K])
// 128x64 tile, BK=128 -> only 4 K-iterations (half R4's barrier drains).
// LDS: As 32 KB + Bs 16 KB = 48 KB -> still 2 blocks/CU (below m132's 64 KB
// occupancy cliff). 16-chunk XOR swizzle c^(r&15): 256 B row stride would be
// 16-way conflicted unswizzled; swizzled b128 reads are 2-way = free.
// 4 waves (2m x 2n, each 64x32). XCD swizzle: A stripe L2-resident per XCD.
// ---------------------------------------------------------------------------
__global__ __launch_bounds__(256) void gemm_kernel(
    const unsigned short* __restrict__ xb,   // bf16 [8192][512]
    const unsigned short* __restrict__ wt,   // bf16 [512][512]
    float* __restrict__ out,                 // fp32 [8192][512]
    const float* __restrict__ partials,      // [512]
    float* diff_slot)
{
    __shared__ unsigned short As[128 * 128]; // 32 KB [m][k], xor-swizzled chunks
    __shared__ unsigned short Bs[64 * 128];  // 16 KB [n][k], xor-swizzled chunks

    const int tid  = threadIdx.x;
    const int wave = tid >> 6;
    const int lane = tid & 63;

    // block swizzle: XCD x (= flat&7 heuristic) owns m-tiles [x*8, x*8+8)
    const int flat = blockIdx.x;             // 0..511
    const int xcd  = flat & 7;
    const int sub  = flat >> 3;              // 0..63
    const int nt   = sub & 7;
    const int mt   = xcd * 8 + (sub >> 3);   // 0..63
    const int m0 = mt * 128;
    const int n0 = nt * 64;
    const int wm = (wave >> 1) * 64;
    const int wn = (wave & 1) * 32;

    // staging: groups of 4 rows x 16 chunks (1 KB = one wave-instr);
    // lane -> (row srow, dest chunk pos); source chunk = pos ^ (row&15)
    const int srow = lane >> 4;              // 0..3 row within group
    const int pos  = lane & 15;              // dest chunk position
    // fragments
    const int mrow = lane & 15;
    const int cq   = lane >> 4;              // 0..3

    floatx4 acc[4][2] = {};

    for (int k0 = 0; k0 < KDIM; k0 += 128) {
        __syncthreads();
#pragma unroll
        for (int c = 0; c < 8; ++c) {        // A: 32 groups of 4 rows; 8/wave
            const int g = wave * 8 + c;
            const int rloc = g * 4 + srow;                  // 0..127
            const int cs = pos ^ (rloc & 15);               // source chunk
            async16(xb + (size_t)(m0 + rloc) * KDIM + k0 + cs * 8, (char*)As + g * 1024);
        }
#pragma unroll
        for (int c = 0; c < 4; ++c) {        // B: 16 groups of 4 rows; 4/wave
            const int g = wave * 4 + c;
            const int rloc = g * 4 + srow;                  // 0..63
            const int cs = pos ^ (rloc & 15);
            async16(wt + (size_t)(n0 + rloc) * KDIM + k0 + cs * 8, (char*)Bs + g * 1024);
        }
        __syncthreads();

#pragma unroll
        for (int ks = 0; ks < 4; ++ks) {     // 4 K-substeps of 32
            bf16x8 a[4], b[2];
#pragma unroll
            for (int i = 0; i < 4; ++i) {
                const int r = wm + i * 16 + mrow;
                const int c = ks * 4 + cq;                  // logical chunk 0..15
                a[i] = *reinterpret_cast<const bf16x8*>(&As[r * 128 + ((c ^ (r & 15)) * 8)]);
            }
#pragma unroll
            for (int j = 0; j < 2; ++j) {
                const int r = wn + j * 16 + mrow;
                const int c = ks * 4 + cq;
                b[j] = *reinterpret_cast<const bf16x8*>(&Bs[r * 128 + ((c ^ (r & 15)) * 8)]);
            }
#pragma unroll
            for (int i = 0; i < 4; ++i)
#pragma unroll
                for (int j = 0; j < 2; ++j)
                    acc[i][j] = __builtin_amdgcn_mfma_f32_16x16x32_bf16(a[i], b[j], acc[i][j], 0, 0, 0);
        }
    }

    // C/D layout: col = lane&15, row = (lane>>4)*4 + reg  (m89-verified)
    const int col = lane & 15;
    const int rbase = (lane >> 4) * 4;
#pragma unroll
    for (int i = 0; i < 4; ++i)
#pragma unroll
        for (int j = 0; j < 2; ++j)
#pragma unroll
            for (int r = 0; r < 4; ++r) {
                const int mm = m0 + wm + i * 16 + rbase + r;
                const int nn = n0 + wn + j * 16 + col;
                out[(size_t)mm * NDIM + nn] = acc[i][j][r];
            }

    // diff reduction (one wave of one block)
    if (flat == 0 && wave == 0 && diff_slot) {
        float s = 0.f;
#pragma unroll
        for (int q = 0; q < 8; ++q) s += partials[lane + 64 * q];
#pragma unroll
        for (int off = 32; off > 0; off >>= 1) s += __shfl_down(s, off, 64);
        if (lane == 0) diff_slot[0] = s * (1.f / (NROWS * DQ));
    }
}

// ---------------------------------------------------------------------------
extern "C" void kernel_launch(void* const* d_in, const int* in_sizes, int n_in,
                              void* d_out, int out_size, void* d_ws, size_t ws_size,
                              hipStream_t stream)
{
    const float* x      = (const float*)d_in[0];
    const float* weight = (const float*)d_in[1];
    const float* embed  = (const float*)d_in[2];
    const int*   use_qw = (const int*)d_in[3];
    float* out = (float*)d_out;

    // ws layout: [0,512K) W^T bf16 ; [512K,514K) diff partials ; [1M,9M) x bf16
    unsigned short* wt = (unsigned short*)d_ws;
    float* partials    = (float*)((char*)d_ws + (512u << 10));
    unsigned short* xb = (unsigned short*)((char*)d_ws + (1u << 20));

    float* diff_slot = (out_size > BATCH * NDIM) ? (out + (size_t)BATCH * NDIM) : nullptr;

    fused_prep_vq<<<VQ_BLOCKS + CONV_BLOCKS, 256, 0, stream>>>(
        x, weight, embed, xb, wt, partials, use_qw);
    gemm_kernel<<<512, 256, 0, stream>>>(xb, wt, out, partials, diff_slot);
}